// Round 2
// baseline (3047.549 us; speedup 1.0000x reference)
//
#include <hip/hip_runtime.h>
#include <hip/hip_bf16.h>

// Problem constants (B,S,N,F,H,E) = (4,8,4000,64,128,32000)
#define B_  4
#define S_  8
#define N_  4000
#define F_  64
#define H_  128
#define E_  32000
#define G_  (B_*S_)        // 32 graphs
#define GN_ (G_*N_)        // 128000 node rows
#define M_  (B_*N_)        // 16000 LSTM rows
#define GE_ (G_*E_)        // 1,024,000 edges total

// f32 weight scratch offsets (floats)
#define OFF_W0S 0
#define OFF_B0S 8192
#define OFF_W0D 8320
#define OFF_B0D 16512
#define OFF_W1S 16640
#define OFF_B1S 33024
#define OFF_W1D 33152
#define OFF_B1D 49536
#define OFF_WIH 49664
#define OFF_WHH 115200
#define OFF_BIH 180736
#define OFF_BHH 181248
#define OFF_WP  181760
#define OFF_BP  189952
#define WCV_TOTAL 190016

__device__ inline float sigmf(float x){ return 1.0f/(1.0f + __expf(-x)); }
__device__ inline float loadf(const void* p, long i, int isf32){
    return isf32 ? ((const float*)p)[i]
                 : __bfloat162float(((const __hip_bfloat16*)p)[i]);
}

// ---------------- dtype sniff ----------------
// edge_weight is uniform [0,1): as bf16 every 16-bit half is <= 0x3F80 (1.0);
// as f32 the low halves are ~uniform random 16-bit. 256 probes -> P(err)~1e-155.
__global__ void sniff_kernel(const unsigned int* __restrict__ ew, int* __restrict__ flag){
    __shared__ int s;
    if (threadIdx.x == 0) s = 0;
    __syncthreads();
    unsigned int lo = ew[threadIdx.x] & 0xFFFFu;
    if (lo > 0x3F80u) atomicOr(&s, 1);
    __syncthreads();
    if (threadIdx.x == 0) flag[0] = s;   // 1 => inputs are f32
}

// ---------------- weight conversion to f32 scratch ----------------
struct WSeg { const void* src; int base; int n; };
struct WDesc { WSeg seg[14]; };
__global__ void convert_weights(WDesc d, float* __restrict__ dst, const int* __restrict__ flag){
    int isf32 = flag[0];
    int idx = blockIdx.x*256 + threadIdx.x;
    #pragma unroll
    for (int s=0;s<14;s++){
        int off = idx - d.seg[s].base;
        if (off >= 0 && off < d.seg[s].n){
            dst[idx] = loadf(d.seg[s].src, off, isf32);
            return;
        }
    }
}

// ---------------- degree accumulation ----------------
__global__ void deg_kernel(const int* __restrict__ ei, const void* __restrict__ ew,
                           const int* __restrict__ flag,
                           float* __restrict__ deg_out, float* __restrict__ deg_in){
    int isf32 = flag[0];
    int idx = blockIdx.x*256 + threadIdx.x;
    if (idx >= GE_) return;
    int g = idx / E_, e = idx - g*E_;
    const int* eib = ei + g*2*E_;
    int src = eib[e], dst = eib[E_ + e];
    float w = loadf(ew, idx, isf32);
    atomicAdd(deg_out + g*N_ + src, w);
    atomicAdd(deg_in  + g*N_ + dst, w);
}

// ---------------- edge norm ----------------
__global__ void norm_kernel(const int* __restrict__ ei, const void* __restrict__ ew,
                            const int* __restrict__ flag,
                            const float* __restrict__ deg_out, const float* __restrict__ deg_in,
                            float* __restrict__ nrm){
    int isf32 = flag[0];
    int idx = blockIdx.x*256 + threadIdx.x;
    if (idx >= GE_) return;
    int g = idx / E_, e = idx - g*E_;
    const int* eib = ei + g*2*E_;
    int src = eib[e], dst = eib[E_ + e];
    float dout = deg_out[g*N_ + src], din = deg_in[g*N_ + dst];
    float io = dout > 0.f ? rsqrtf(fmaxf(dout, 1e-12f)) : 0.f;
    float ii = din  > 0.f ? rsqrtf(fmaxf(din , 1e-12f)) : 0.f;
    nrm[idx] = loadf(ew, idx, isf32) * io * ii;
}

// ---------------- edge scatter, layer 0 (x_seq input, dynamic dtype, F=64) ----------------
__global__ void scatter0(const int* __restrict__ ei, const float* __restrict__ nrm,
                         const void* __restrict__ x, const int* __restrict__ flag,
                         float* __restrict__ agg_f, float* __restrict__ agg_b){
    int isf32 = flag[0];
    int lane = threadIdx.x & 63;
    int esub = threadIdx.x >> 6;       // 4 edges / block
    int eidx = blockIdx.x*4 + esub;
    int g = eidx / E_, e = eidx - g*E_;
    const int* eib = ei + g*2*E_;
    int src = eib[e], dst = eib[E_ + e];
    float nv = nrm[eidx];
    float xs = loadf(x, (long)(g*N_+src)*64 + lane, isf32);
    float xd = loadf(x, (long)(g*N_+dst)*64 + lane, isf32);
    atomicAdd(agg_f + (long)(g*N_+dst)*64 + lane, nv*xs);   // A_hat x
    atomicAdd(agg_b + (long)(g*N_+src)*64 + lane, nv*xd);   // A_hat^T x
}

// ---------------- edge scatter, layer 1 (f32 hbuf input, F=128) ----------------
__global__ void scatter1(const int* __restrict__ ei, const float* __restrict__ nrm,
                         const float* __restrict__ x,
                         float* __restrict__ agg_f, float* __restrict__ agg_b){
    int lane = threadIdx.x & 127;
    int esub = threadIdx.x >> 7;       // 2 edges / block
    int eidx = blockIdx.x*2 + esub;
    int g = eidx / E_, e = eidx - g*E_;
    const int* eib = ei + g*2*E_;
    int src = eib[e], dst = eib[E_ + e];
    float nv = nrm[eidx];
    float xs = x[(long)(g*N_+src)*128 + lane];
    float xd = x[(long)(g*N_+dst)*128 + lane];
    atomicAdd(agg_f + (long)(g*N_+dst)*128 + lane, nv*xs);
    atomicAdd(agg_b + (long)(g*N_+src)*128 + lane, nv*xd);
}

// --------- h = 0.5*(agg_f @ Ws^T + bs) + 0.5*(agg_b @ Wd^T + bd) ---------
// block: 128 threads (one per output col j), 16 rows per block. Weights f32.
template<int K>
__global__ __launch_bounds__(128) void gcn_gemm(
        const float* __restrict__ Afb, const float* __restrict__ Abb,
        const float* __restrict__ Ws, const float* __restrict__ bs,
        const float* __restrict__ Wd, const float* __restrict__ bd,
        float* __restrict__ out){
    __shared__ float4 Af[16][K/4];
    __shared__ float4 Ab[16][K/4];
    int j = threadIdx.x;
    int row0 = blockIdx.x * 16;
    const float4* Af_g = (const float4*)(Afb + (size_t)row0*K);
    const float4* Ab_g = (const float4*)(Abb + (size_t)row0*K);
    for (int t = j; t < 16*(K/4); t += 128) {
        ((float4*)Af)[t] = Af_g[t];
        ((float4*)Ab)[t] = Ab_g[t];
    }
    __syncthreads();
    float acc[16];
    #pragma unroll
    for (int r=0;r<16;r++) acc[r]=0.f;
    const float4* Wsv = (const float4*)(Ws + j*K);
    const float4* Wdv = (const float4*)(Wd + j*K);
    for (int k4=0;k4<K/4;k4++){
        float4 a = Wsv[k4];
        float4 b = Wdv[k4];
        #pragma unroll
        for (int r=0;r<16;r++){
            float4 fa = Af[r][k4];
            float4 fb = Ab[r][k4];
            acc[r] += a.x*fa.x + a.y*fa.y + a.z*fa.z + a.w*fa.w
                    + b.x*fb.x + b.y*fb.y + b.z*fb.z + b.w*fb.w;
        }
    }
    float bias = 0.5f*(bs[j] + bd[j]);
    #pragma unroll
    for (int r=0;r<16;r++) out[(size_t)(row0+r)*H_ + j] = 0.5f*acc[r] + bias;
}

// ---------------- fused LSTM (8 steps) + final projection ----------------
// block: 512 threads (one per gate j), 16 LSTM rows per block.
// x_t for row m at step t is hsrc row (m*8 + t). Output row = m directly.
__global__ __launch_bounds__(512) void lstm_kernel(
        const float* __restrict__ hsrc, const float* __restrict__ wcv,
        const int* __restrict__ flag, void* __restrict__ out){
    __shared__ float4 xh[16][64];      // per row: [0:32) float4 = x_t (128f), [32:64) = h
    __shared__ float  carr[16][128];
    __shared__ float  garr[16][512];
    float* xhf = (float*)xh;           // row stride 256 floats
    int isf32 = flag[0];
    int tid = threadIdx.x;
    int m0 = blockIdx.x * 16;
    for (int t=tid; t<16*128; t+=512){ int r=t>>7, k=t&127; carr[r][k]=0.f; xhf[r*256+128+k]=0.f; }
    __syncthreads();
    const float4* Wihv = (const float4*)(wcv + OFF_WIH + tid*128);
    const float4* Whhv = (const float4*)(wcv + OFF_WHH + tid*128);
    float bias = wcv[OFF_BIH + tid] + wcv[OFF_BHH + tid];
    for (int step=0; step<8; step++){
        for (int t=tid; t<16*128; t+=512){
            int r=t>>7, k=t&127;
            xhf[r*256+k] = hsrc[(size_t)((m0+r)*8+step)*128 + k];
        }
        __syncthreads();
        float acc[16];
        #pragma unroll
        for (int r=0;r<16;r++) acc[r]=bias;
        for (int k4=0;k4<32;k4++){
            float4 a = Wihv[k4];
            float4 b = Whhv[k4];
            #pragma unroll
            for (int r=0;r<16;r++){
                float4 xv = xh[r][k4];
                float4 hv = xh[r][32+k4];
                acc[r] += a.x*xv.x + a.y*xv.y + a.z*xv.z + a.w*xv.w
                        + b.x*hv.x + b.y*hv.y + b.z*hv.z + b.w*hv.w;
            }
        }
        #pragma unroll
        for (int r=0;r<16;r++) garr[r][tid] = acc[r];
        __syncthreads();
        for (int t=tid; t<16*128; t+=512){
            int r=t>>7, k=t&127;
            float gi=garr[r][k], gf=garr[r][128+k], gg=garr[r][256+k], go=garr[r][384+k];
            float c = sigmf(gf)*carr[r][k] + sigmf(gi)*tanhf(gg);
            carr[r][k]=c;
            xhf[r*256+128+k] = sigmf(go)*tanhf(c);
        }
        __syncthreads();
    }
    // out[m][q] = h_last . Wp[q] + bp[q], q in [0,64)
    for (int t=tid; t<16*64; t+=512){
        int r=t>>6, q=t&63;
        float acc=0.f;
        const float4* wr = (const float4*)(wcv + OFF_WP + q*128);
        for (int k4=0;k4<32;k4++){
            float4 a = wr[k4];
            float4 hv = xh[r][32+k4];
            acc += a.x*hv.x + a.y*hv.y + a.z*hv.z + a.w*hv.w;
        }
        float v = acc + wcv[OFF_BP + q];
        long o = (long)(m0+r)*64 + q;
        if (isf32) ((float*)out)[o] = v;
        else       ((__hip_bfloat16*)out)[o] = __float2bfloat16(v);
    }
}

extern "C" void kernel_launch(void* const* d_in, const int* in_sizes, int n_in,
                              void* d_out, int out_size, void* d_ws, size_t ws_size,
                              hipStream_t stream){
    const void* x_seq      = d_in[0];
    const int*  edge_index = (const int*)d_in[1];
    const void* edge_weight= d_in[2];

    int*   flag  = (int*)d_ws;
    float* wsf   = (float*)d_ws;
    float* wcv   = wsf + 16;                 // 190,016 floats f32 weights
    float* deg_o = wcv + WCV_TOTAL;          // 128,000
    float* deg_i = deg_o + GN_;              // 128,000
    float* nrm   = deg_i + GN_;              // 1,024,000
    float* aggF  = nrm + GE_;                // 16,384,000
    float* aggB  = aggF + (size_t)GN_*H_;    // 16,384,000
    float* hbuf  = aggB + (size_t)GN_*H_;    // 16,384,000
    // total ~193.1 MiB

    // dtype sniff + weight conversion
    sniff_kernel<<<1, 256, 0, stream>>>((const unsigned int*)edge_weight, flag);
    WDesc wd;
    wd.seg[0]  = { d_in[3],  OFF_W0S, 8192  };  // W0_s
    wd.seg[1]  = { d_in[4],  OFF_B0S, 128   };  // b0_s
    wd.seg[2]  = { d_in[5],  OFF_W0D, 8192  };  // W0_d
    wd.seg[3]  = { d_in[6],  OFF_B0D, 128   };  // b0_d
    wd.seg[4]  = { d_in[7],  OFF_W1S, 16384 };  // W1_s
    wd.seg[5]  = { d_in[8],  OFF_B1S, 128   };  // b1_s
    wd.seg[6]  = { d_in[9],  OFF_W1D, 16384 };  // W1_d
    wd.seg[7]  = { d_in[10], OFF_B1D, 128   };  // b1_d
    wd.seg[8]  = { d_in[11], OFF_WIH, 65536 };  // lstm_Wih
    wd.seg[9]  = { d_in[12], OFF_WHH, 65536 };  // lstm_Whh
    wd.seg[10] = { d_in[13], OFF_BIH, 512   };  // lstm_bih
    wd.seg[11] = { d_in[14], OFF_BHH, 512   };  // lstm_bhh
    wd.seg[12] = { d_in[15], OFF_WP,  8192  };  // Wp
    wd.seg[13] = { d_in[16], OFF_BP,  64    };  // bp
    convert_weights<<<(WCV_TOTAL+255)/256, 256, 0, stream>>>(wd, wcv, flag);

    hipMemsetAsync(deg_o, 0, (size_t)(2*GN_)*sizeof(float), stream);
    hipMemsetAsync(aggF,  0, (size_t)(2ll*GN_*H_)*sizeof(float), stream);

    deg_kernel <<<(GE_+255)/256, 256, 0, stream>>>(edge_index, edge_weight, flag, deg_o, deg_i);
    norm_kernel<<<(GE_+255)/256, 256, 0, stream>>>(edge_index, edge_weight, flag, deg_o, deg_i, nrm);

    // layer 0: F=64 input (x_seq, dynamic dtype)
    scatter0<<<GE_/4, 256, 0, stream>>>(edge_index, nrm, x_seq, flag, aggF, aggB);
    gcn_gemm<64><<<GN_/16, 128, 0, stream>>>(aggF, aggB,
        wcv+OFF_W0S, wcv+OFF_B0S, wcv+OFF_W0D, wcv+OFF_B0D, hbuf);

    // layer 1: F=128 input (f32 hbuf)
    hipMemsetAsync(aggF, 0, (size_t)(2ll*GN_*H_)*sizeof(float), stream);
    scatter1<<<GE_/2, 256, 0, stream>>>(edge_index, nrm, hbuf, aggF, aggB);
    gcn_gemm<128><<<GN_/16, 128, 0, stream>>>(aggF, aggB,
        wcv+OFF_W1S, wcv+OFF_B1S, wcv+OFF_W1D, wcv+OFF_B1D, hbuf);

    // fused LSTM (8 steps) + projection -> out
    lstm_kernel<<<M_/16, 512, 0, stream>>>(hbuf, wcv, flag, d_out);
}